// Round 14
// baseline (2944.082 us; speedup 1.0000x reference)
//
#include <hip/hip_runtime.h>

#define H 64
#define T_STEPS 2048

typedef _Float16 h2_t __attribute__((ext_vector_type(2)));
typedef _Float16 h8_t __attribute__((ext_vector_type(8)));

__device__ __forceinline__ float tanh_f(float x) {
    return 2.0f / (1.0f + __expf(-2.0f * x)) - 1.0f;
}

// R14 core: v_fma_mix_f32 -- f16 inputs, fp32 FMA, FULL VALU rate (2 cyc).
// R13 evidence: VALUBusy 73% at ~2050 busy-cyc/SIMD/phase == 4x the issue
// count if dot2 were full-rate -> v_dot2_f32_f16 is ~quarter-rate on
// gfx950 (0.25 MAC/cyc/lane, HALF of plain v_fma_f32). fma_mix gives
// 0.5 MAC/cyc/lane at the same f16 register footprint and f32 accumulate.
// c += lo(a)*lo(b); c += hi(a)*hi(b)
__device__ __forceinline__ void mix2(float& c, h2_t a, h2_t b) {
    asm("v_fma_mix_f32 %0, %1, %2, %0 op_sel_hi:[1,1,0]"
        : "+v"(c) : "v"(a), "v"(b));
    asm("v_fma_mix_f32 %0, %1, %2, %0 op_sel:[1,1,0] op_sel_hi:[1,1,0]"
        : "+v"(c) : "v"(a), "v"(b));
}

#define SUB2(v, i) __builtin_shufflevector((v), (v), (i), (i) + 1)

__device__ __forceinline__ float d8m(h8_t wv, h8_t hv, float acc) {
    mix2(acc, SUB2(wv, 0), SUB2(hv, 0));
    mix2(acc, SUB2(wv, 2), SUB2(hv, 2));
    mix2(acc, SUB2(wv, 4), SUB2(hv, 4));
    mix2(acc, SUB2(wv, 6), SUB2(hv, 6));
    return acc;
}

// Full 64-wide row dot, 4 independent accumulator chains (ILP).
#define DOTROW8(Wa, Wb, Wc, Wd, We, Wf, Wg, Wh, hp) ({                  \
    float _a0 = 0.f, _a1 = 0.f, _a2 = 0.f, _a3 = 0.f;                   \
    _a0 = d8m(Wa, (hp)[0], _a0); _a1 = d8m(Wb, (hp)[1], _a1);           \
    _a2 = d8m(Wc, (hp)[2], _a2); _a3 = d8m(Wd, (hp)[3], _a3);           \
    _a0 = d8m(We, (hp)[4], _a0); _a1 = d8m(Wf, (hp)[5], _a1);           \
    _a2 = d8m(Wg, (hp)[6], _a2); _a3 = d8m(Wh, (hp)[7], _a3);           \
    (_a0 + _a1) + (_a2 + _a3); })

// load 16 fp32 weights -> two h8_t (load-time only)
__device__ __forceinline__ void cvt16(const float* __restrict__ src,
                                      h8_t& a, h8_t& b) {
    const float4* p = (const float4*)src;
    float4 v0 = p[0], v1 = p[1], v2 = p[2], v3 = p[3];
    a[0] = (_Float16)v0.x; a[1] = (_Float16)v0.y;
    a[2] = (_Float16)v0.z; a[3] = (_Float16)v0.w;
    a[4] = (_Float16)v1.x; a[5] = (_Float16)v1.y;
    a[6] = (_Float16)v1.z; a[7] = (_Float16)v1.w;
    b[0] = (_Float16)v2.x; b[1] = (_Float16)v2.y;
    b[2] = (_Float16)v2.z; b[3] = (_Float16)v2.w;
    b[4] = (_Float16)v3.x; b[5] = (_Float16)v3.y;
    b[6] = (_Float16)v3.z; b[7] = (_Float16)v3.w;
}

// Structure identical to R13 (full-row lanes, in-wave cell update via
// __shfl_xor(16/32/48), one barrier/phase, 3-layer software pipeline,
// h double-buffered in f16 LDS). Only the MAC instruction changed.
__global__ __launch_bounds__(768)
void lstm3_wave(const float* __restrict__ x,
                const float* __restrict__ Wih0, const float* __restrict__ Whh0,
                const float* __restrict__ bih0, const float* __restrict__ bhh0,
                const float* __restrict__ Wih1, const float* __restrict__ Whh1,
                const float* __restrict__ bih1, const float* __restrict__ bhh1,
                const float* __restrict__ Wih2, const float* __restrict__ Whh2,
                const float* __restrict__ bih2, const float* __restrict__ bhh2,
                const float* __restrict__ Wout, const float* __restrict__ bout,
                float* __restrict__ out)
{
    __shared__ __align__(16) float xs[T_STEPS * 2];       // 16 KB input seq
    __shared__ __align__(16) _Float16 h0b[2][H];          // h, 2 slots, f16
    __shared__ __align__(16) _Float16 h1b[2][H];
    __shared__ __align__(16) _Float16 h2b[2][H];
    __shared__ __align__(16) float h2f[H];                // fp32 h2 (proj)

    const int tid   = threadIdx.x;
    const int b     = blockIdx.x;
    const int layer = tid >> 8;              // wave-uniform: 0,1,2
    const int l     = tid & 63;
    const int gate  = l >> 4;                // 0:i 1:f 2:g 3:o (lane-varying)
    const int cell  = ((tid >> 6) & 3) * 16 + (l & 15);
    const int r     = gate * H + cell;       // gate row 0..255

    // ---- stage x[b,:,:] (1024 float4) ----
    {
        const float4* xsrc = (const float4*)(x + (size_t)b * T_STEPS * 2);
        ((float4*)xs)[tid] = xsrc[tid];
        if (tid < 256) ((float4*)xs)[tid + 768] = xsrc[tid + 768];
    }

    // ---- this lane's full weight row(s) -> 16 h8 = 32 VGPRs ----
    const float* m1 = (layer == 0) ? (Whh0 + r * H)
                    : (layer == 1) ? (Wih1 + r * H) : (Wih2 + r * H);
    const float* m2 = (layer == 2) ? (Whh2 + r * H) : (Whh1 + r * H);
    h8_t W0, W1, W2, W3, W4, W5, W6, W7, W8, W9, Wa, Wb, Wc, Wd, We, Wf;
    cvt16(m1,      W0, W1); cvt16(m1 + 16, W2, W3);
    cvt16(m1 + 32, W4, W5); cvt16(m1 + 48, W6, W7);
    cvt16(m2,      W8, W9); cvt16(m2 + 16, Wa, Wb);
    cvt16(m2 + 32, Wc, Wd); cvt16(m2 + 48, We, Wf);
    float wx0 = 0.f, wx1 = 0.f;
    if (layer == 0) { wx0 = Wih0[r * 2]; wx1 = Wih0[r * 2 + 1]; }
    const float* bip = (layer == 0) ? bih0 : (layer == 1) ? bih1 : bih2;
    const float* bhp = (layer == 0) ? bhh0 : (layer == 1) ? bhh1 : bhh2;
    float bias = bip[r] + bhp[r];

    asm volatile("" : "+v"(W0), "+v"(W1), "+v"(W2), "+v"(W3));
    asm volatile("" : "+v"(W4), "+v"(W5), "+v"(W6), "+v"(W7));
    asm volatile("" : "+v"(W8), "+v"(W9), "+v"(Wa), "+v"(Wb));
    asm volatile("" : "+v"(Wc), "+v"(Wd), "+v"(We), "+v"(Wf));
    asm volatile("" : "+v"(wx0), "+v"(wx1), "+v"(bias));

    if (tid < H) {
        _Float16 z = (_Float16)0.f;
        h0b[0][tid] = z; h0b[1][tid] = z;
        h1b[0][tid] = z; h1b[1][tid] = z;
        h2b[0][tid] = z; h2b[1][tid] = z;
    }
    float cst = 0.f;   // this lane's copy of its cell state (4 identical/cell)
    __syncthreads();

    const bool isg = (gate == 2);

#pragma unroll 1
    for (int p = 0; p < T_STEPS + 2; ++p) {
        const int s = (p + 1) & 1;     // read slot
        const int w = p & 1;           // write slot
        const bool on = (layer == 0) ? (p < T_STEPS)
                      : (layer == 1) ? (p >= 1 && p < T_STEPS + 1)
                                     : (p >= 2);            // wave-uniform
        if (on) {
            float pa;
            if (layer == 0) {
                const h8_t* hp = (const h8_t*)h0b[s];
                float2 xt = *(const float2*)&xs[2 * p];
                pa = bias + wx0 * xt.x + wx1 * xt.y
                   + DOTROW8(W0, W1, W2, W3, W4, W5, W6, W7, hp);
            } else if (layer == 1) {
                pa = bias
                   + DOTROW8(W0, W1, W2, W3, W4, W5, W6, W7, (const h8_t*)h0b[s])
                   + DOTROW8(W8, W9, Wa, Wb, Wc, Wd, We, Wf, (const h8_t*)h1b[s]);
            } else {
                pa = bias
                   + DOTROW8(W0, W1, W2, W3, W4, W5, W6, W7, (const h8_t*)h1b[s])
                   + DOTROW8(W8, W9, Wa, Wb, Wc, Wd, We, Wf, (const h8_t*)h2b[s]);
            }
            // branchless activation: sigmoid(pa) or tanh(pa) for g-gate
            float zz  = isg ? (-2.0f * pa) : (-pa);
            float ex  = __expf(zz);
            float rr  = 1.0f / (1.0f + ex);
            float act = isg ? (2.0f * rr - 1.0f) : rr;
            // in-wave gather of the cell's 4 gate activations
            float a16 = __shfl_xor(act, 16);   // gate^1
            float a32 = __shfl_xor(act, 32);   // gate^2
            float a48 = __shfl_xor(act, 48);   // gate^3
            const bool b0 = (gate & 1), b1 = (gate & 2);
            float q0 = b0 ? a16 : act, q1 = b0 ? act : a16;
            float q2 = b0 ? a48 : a32, q3 = b0 ? a32 : a48;
            float gi = b1 ? q2 : q0;           // arr[0] = i
            float gf = b1 ? q3 : q1;           // arr[1] = f
            float gg = b1 ? q0 : q2;           // arr[2] = g
            float go = b1 ? q1 : q3;           // arr[3] = o
            cst = gf * cst + gi * gg;
            float hh = go * tanh_f(cst);
            if (l < 16) {                      // gate-0 lane writes its cell's h
                _Float16 hx = (_Float16)hh;
                if (layer == 0)      h0b[w][cell] = hx;
                else if (layer == 1) h1b[w][cell] = hx;
                else               { h2b[w][cell] = hx; h2f[cell] = hh; }
            }
        }
        __syncthreads();
    }

    // ---- fused projection: out[b,:] = h2_last @ Wout^T + bout ----
    if (tid < 11) {
        float acc = bout[tid];
#pragma unroll
        for (int jj = 0; jj < H; ++jj)
            acc += Wout[tid * H + jj] * h2f[jj];
        out[b * 11 + tid] = acc;
    }
}

extern "C" void kernel_launch(void* const* d_in, const int* in_sizes, int n_in,
                              void* d_out, int out_size, void* d_ws, size_t ws_size,
                              hipStream_t stream) {
    const float* x    = (const float*)d_in[0];
    const float* Wih0 = (const float*)d_in[1];
    const float* Whh0 = (const float*)d_in[2];
    const float* bih0 = (const float*)d_in[3];
    const float* bhh0 = (const float*)d_in[4];
    const float* Wih1 = (const float*)d_in[5];
    const float* Whh1 = (const float*)d_in[6];
    const float* bih1 = (const float*)d_in[7];
    const float* bhh1 = (const float*)d_in[8];
    const float* Wih2 = (const float*)d_in[9];
    const float* Whh2 = (const float*)d_in[10];
    const float* bih2 = (const float*)d_in[11];
    const float* bhh2 = (const float*)d_in[12];
    const float* Wout = (const float*)d_in[13];
    const float* bout = (const float*)d_in[14];
    float* out = (float*)d_out;

    lstm3_wave<<<256, 768, 0, stream>>>(x,
        Wih0, Whh0, bih0, bhh0,
        Wih1, Whh1, bih1, bhh1,
        Wih2, Whh2, bih2, bhh2,
        Wout, bout, out);
}

// Round 15
// 2869.748 us; speedup vs baseline: 1.0259x; 1.0259x over previous
//
#include <hip/hip_runtime.h>

#define H 64
#define T_STEPS 2048

typedef _Float16 h2_t __attribute__((ext_vector_type(2)));
typedef _Float16 h8_t __attribute__((ext_vector_type(8)));

__device__ __forceinline__ float tanh_f(float x) {
    return 2.0f / (1.0f + __expf(-2.0f * x)) - 1.0f;
}

#define SUB2(v, i) __builtin_shufflevector((v), (v), (i), (i) + 1)

// R15 core: v_pk_fma_f16 (VOP3P packed f16 FMA, the full-rate packed-math
// path: 2 MAC/inst @ 2 cyc). Measured rates from R13/R14 busy-cycle math:
// v_dot2_f32_f16 ~8 cyc, v_fma_mix_f32 ~6.5 cyc -- both slow-pipe. C-level
// h2_t arithmetic compiles to v_pk_fma_f16.
// Chain = ONE h8 unit (4 pk_fma): each f16 half-sum covers only 4 products
// (mag <= 0.5) -> accumulation err ~5e-4 rms per 64-dot, well in budget.
__device__ __forceinline__ h2_t pk4(h8_t wv, h8_t hv, h2_t acc) {
    acc += SUB2(wv, 0) * SUB2(hv, 0);
    acc += SUB2(wv, 2) * SUB2(hv, 2);
    acc += SUB2(wv, 4) * SUB2(hv, 4);
    acc += SUB2(wv, 6) * SUB2(hv, 6);
    return acc;
}
__device__ __forceinline__ float fold2(h2_t a) {   // f32 promote + add (full rate)
    return (float)a[0] + (float)a[1];
}

// Full 64-wide row dot: 8 independent pk-chains, fp32 tree combine.
#define DOTROW8(Wa, Wb, Wc, Wd, We, Wf, Wg, Wh, hp) ({                   \
    h2_t _z; _z[0] = (_Float16)0.f; _z[1] = (_Float16)0.f;               \
    h2_t _c0 = pk4(Wa, (hp)[0], _z), _c1 = pk4(Wb, (hp)[1], _z);         \
    h2_t _c2 = pk4(Wc, (hp)[2], _z), _c3 = pk4(Wd, (hp)[3], _z);         \
    h2_t _c4 = pk4(We, (hp)[4], _z), _c5 = pk4(Wf, (hp)[5], _z);         \
    h2_t _c6 = pk4(Wg, (hp)[6], _z), _c7 = pk4(Wh, (hp)[7], _z);         \
    ((fold2(_c0) + fold2(_c1)) + (fold2(_c2) + fold2(_c3)))              \
  + ((fold2(_c4) + fold2(_c5)) + (fold2(_c6) + fold2(_c7))); })

// load 16 fp32 weights -> two h8_t (load-time only)
__device__ __forceinline__ void cvt16(const float* __restrict__ src,
                                      h8_t& a, h8_t& b) {
    const float4* p = (const float4*)src;
    float4 v0 = p[0], v1 = p[1], v2 = p[2], v3 = p[3];
    a[0] = (_Float16)v0.x; a[1] = (_Float16)v0.y;
    a[2] = (_Float16)v0.z; a[3] = (_Float16)v0.w;
    a[4] = (_Float16)v1.x; a[5] = (_Float16)v1.y;
    a[6] = (_Float16)v1.z; a[7] = (_Float16)v1.w;
    b[0] = (_Float16)v2.x; b[1] = (_Float16)v2.y;
    b[2] = (_Float16)v2.z; b[3] = (_Float16)v2.w;
    b[4] = (_Float16)v3.x; b[5] = (_Float16)v3.y;
    b[6] = (_Float16)v3.z; b[7] = (_Float16)v3.w;
}

// Structure identical to R13 (full-row lanes, in-wave cell update via
// __shfl_xor(16/32/48), one barrier/phase, 3-layer software pipeline,
// h double-buffered in f16 LDS). Only the MAC instruction changed.
__global__ __launch_bounds__(768)
void lstm3_wave(const float* __restrict__ x,
                const float* __restrict__ Wih0, const float* __restrict__ Whh0,
                const float* __restrict__ bih0, const float* __restrict__ bhh0,
                const float* __restrict__ Wih1, const float* __restrict__ Whh1,
                const float* __restrict__ bih1, const float* __restrict__ bhh1,
                const float* __restrict__ Wih2, const float* __restrict__ Whh2,
                const float* __restrict__ bih2, const float* __restrict__ bhh2,
                const float* __restrict__ Wout, const float* __restrict__ bout,
                float* __restrict__ out)
{
    __shared__ __align__(16) float xs[T_STEPS * 2];       // 16 KB input seq
    __shared__ __align__(16) _Float16 h0b[2][H];          // h, 2 slots, f16
    __shared__ __align__(16) _Float16 h1b[2][H];
    __shared__ __align__(16) _Float16 h2b[2][H];
    __shared__ __align__(16) float h2f[H];                // fp32 h2 (proj)

    const int tid   = threadIdx.x;
    const int b     = blockIdx.x;
    const int layer = tid >> 8;              // wave-uniform: 0,1,2
    const int l     = tid & 63;
    const int gate  = l >> 4;                // 0:i 1:f 2:g 3:o (lane-varying)
    const int cell  = ((tid >> 6) & 3) * 16 + (l & 15);
    const int r     = gate * H + cell;       // gate row 0..255

    // ---- stage x[b,:,:] (1024 float4) ----
    {
        const float4* xsrc = (const float4*)(x + (size_t)b * T_STEPS * 2);
        ((float4*)xs)[tid] = xsrc[tid];
        if (tid < 256) ((float4*)xs)[tid + 768] = xsrc[tid + 768];
    }

    // ---- this lane's full weight row(s) -> 16 h8 = 32 VGPRs ----
    const float* m1 = (layer == 0) ? (Whh0 + r * H)
                    : (layer == 1) ? (Wih1 + r * H) : (Wih2 + r * H);
    const float* m2 = (layer == 2) ? (Whh2 + r * H) : (Whh1 + r * H);
    h8_t W0, W1, W2, W3, W4, W5, W6, W7, W8, W9, Wa, Wb, Wc, Wd, We, Wf;
    cvt16(m1,      W0, W1); cvt16(m1 + 16, W2, W3);
    cvt16(m1 + 32, W4, W5); cvt16(m1 + 48, W6, W7);
    cvt16(m2,      W8, W9); cvt16(m2 + 16, Wa, Wb);
    cvt16(m2 + 32, Wc, Wd); cvt16(m2 + 48, We, Wf);
    float wx0 = 0.f, wx1 = 0.f;
    if (layer == 0) { wx0 = Wih0[r * 2]; wx1 = Wih0[r * 2 + 1]; }
    const float* bip = (layer == 0) ? bih0 : (layer == 1) ? bih1 : bih2;
    const float* bhp = (layer == 0) ? bhh0 : (layer == 1) ? bhh1 : bhh2;
    float bias = bip[r] + bhp[r];

    asm volatile("" : "+v"(W0), "+v"(W1), "+v"(W2), "+v"(W3));
    asm volatile("" : "+v"(W4), "+v"(W5), "+v"(W6), "+v"(W7));
    asm volatile("" : "+v"(W8), "+v"(W9), "+v"(Wa), "+v"(Wb));
    asm volatile("" : "+v"(Wc), "+v"(Wd), "+v"(We), "+v"(Wf));
    asm volatile("" : "+v"(wx0), "+v"(wx1), "+v"(bias));

    if (tid < H) {
        _Float16 z = (_Float16)0.f;
        h0b[0][tid] = z; h0b[1][tid] = z;
        h1b[0][tid] = z; h1b[1][tid] = z;
        h2b[0][tid] = z; h2b[1][tid] = z;
    }
    float cst = 0.f;   // this lane's copy of its cell state (4 identical/cell)
    __syncthreads();

    const bool isg = (gate == 2);

#pragma unroll 1
    for (int p = 0; p < T_STEPS + 2; ++p) {
        const int s = (p + 1) & 1;     // read slot
        const int w = p & 1;           // write slot
        const bool on = (layer == 0) ? (p < T_STEPS)
                      : (layer == 1) ? (p >= 1 && p < T_STEPS + 1)
                                     : (p >= 2);            // wave-uniform
        if (on) {
            float pa;
            if (layer == 0) {
                const h8_t* hp = (const h8_t*)h0b[s];
                float2 xt = *(const float2*)&xs[2 * p];
                pa = bias + wx0 * xt.x + wx1 * xt.y
                   + DOTROW8(W0, W1, W2, W3, W4, W5, W6, W7, hp);
            } else if (layer == 1) {
                pa = bias
                   + DOTROW8(W0, W1, W2, W3, W4, W5, W6, W7, (const h8_t*)h0b[s])
                   + DOTROW8(W8, W9, Wa, Wb, Wc, Wd, We, Wf, (const h8_t*)h1b[s]);
            } else {
                pa = bias
                   + DOTROW8(W0, W1, W2, W3, W4, W5, W6, W7, (const h8_t*)h1b[s])
                   + DOTROW8(W8, W9, Wa, Wb, Wc, Wd, We, Wf, (const h8_t*)h2b[s]);
            }
            // branchless activation: sigmoid(pa) or tanh(pa) for g-gate
            float zz  = isg ? (-2.0f * pa) : (-pa);
            float ex  = __expf(zz);
            float rr  = 1.0f / (1.0f + ex);
            float act = isg ? (2.0f * rr - 1.0f) : rr;
            // in-wave gather of the cell's 4 gate activations
            float a16 = __shfl_xor(act, 16);   // gate^1
            float a32 = __shfl_xor(act, 32);   // gate^2
            float a48 = __shfl_xor(act, 48);   // gate^3
            const bool b0 = (gate & 1), b1 = (gate & 2);
            float q0 = b0 ? a16 : act, q1 = b0 ? act : a16;
            float q2 = b0 ? a48 : a32, q3 = b0 ? a32 : a48;
            float gi = b1 ? q2 : q0;           // arr[0] = i
            float gf = b1 ? q3 : q1;           // arr[1] = f
            float gg = b1 ? q0 : q2;           // arr[2] = g
            float go = b1 ? q1 : q3;           // arr[3] = o
            cst = gf * cst + gi * gg;
            float hh = go * tanh_f(cst);
            if (l < 16) {                      // gate-0 lane writes its cell's h
                _Float16 hx = (_Float16)hh;
                if (layer == 0)      h0b[w][cell] = hx;
                else if (layer == 1) h1b[w][cell] = hx;
                else               { h2b[w][cell] = hx; h2f[cell] = hh; }
            }
        }
        __syncthreads();
    }

    // ---- fused projection: out[b,:] = h2_last @ Wout^T + bout ----
    if (tid < 11) {
        float acc = bout[tid];
#pragma unroll
        for (int jj = 0; jj < H; ++jj)
            acc += Wout[tid * H + jj] * h2f[jj];
        out[b * 11 + tid] = acc;
    }
}

extern "C" void kernel_launch(void* const* d_in, const int* in_sizes, int n_in,
                              void* d_out, int out_size, void* d_ws, size_t ws_size,
                              hipStream_t stream) {
    const float* x    = (const float*)d_in[0];
    const float* Wih0 = (const float*)d_in[1];
    const float* Whh0 = (const float*)d_in[2];
    const float* bih0 = (const float*)d_in[3];
    const float* bhh0 = (const float*)d_in[4];
    const float* Wih1 = (const float*)d_in[5];
    const float* Whh1 = (const float*)d_in[6];
    const float* bih1 = (const float*)d_in[7];
    const float* bhh1 = (const float*)d_in[8];
    const float* Wih2 = (const float*)d_in[9];
    const float* Whh2 = (const float*)d_in[10];
    const float* bih2 = (const float*)d_in[11];
    const float* bhh2 = (const float*)d_in[12];
    const float* Wout = (const float*)d_in[13];
    const float* bout = (const float*)d_in[14];
    float* out = (float*)d_out;

    lstm3_wave<<<256, 768, 0, stream>>>(x,
        Wih0, Whh0, bih0, bhh0,
        Wih1, Whh1, bih1, bhh1,
        Wih2, Whh2, bih2, bhh2,
        Wout, bout, out);
}